// Round 1
// baseline (11726.377 us; speedup 1.0000x reference)
//
#include <hip/hip_runtime.h>
#include <cstddef>

#define HH 76
#define WW 120
#define NPIX (HH*WW)          // 9120
#define AA 9
#define NANCH (NPIX*AA)       // 82080
#define TOPN 300
#define CIN 1024
#define CMID 512
#define FCDIM 2048
#define KFC (CIN*49)          // 50176

__device__ __forceinline__ float bf2f(unsigned short h) {
    return __uint_as_float(((unsigned int)h) << 16);
}
__device__ __forceinline__ unsigned short f2bf(float f) {
    unsigned int u = __float_as_uint(f);
    unsigned int r = (u + 0x7FFFu + ((u >> 16) & 1u)) >> 16;
    return (unsigned short)r;
}

// ---------------- zero init ----------------
__global__ void zero_kernel(float* __restrict__ p, int n) {
    int i = blockIdx.x * 256 + threadIdx.x;
    if (i < n) p[i] = 0.f;
}

// ---------------- conv 3x3 + bias + relu ----------------
// grid (64, 76), block 128. Each block: 8 output channels, one h row.
__global__ __launch_bounds__(128) void conv3x3_kernel(
    const float* __restrict__ F, const float* __restrict__ Wt,
    const float* __restrict__ Bs, float* __restrict__ out) {
    const int ocb = blockIdx.x;
    const int h = blockIdx.y;
    const int tid = threadIdx.x;
    __shared__ float sIn[8 * 3 * 122];  // 8 ic, 3 rows, 122 padded width
    float acc[8];
#pragma unroll
    for (int i = 0; i < 8; i++) acc[i] = 0.f;
    const int oc0 = ocb * 8;

    for (int c0 = 0; c0 < CIN; c0 += 8) {
        __syncthreads();
        for (int idx = tid; idx < 2928; idx += 128) {
            int ic = idx / 366;
            int rem = idx - ic * 366;
            int r = rem / 122;
            int wp = rem - r * 122 - 1;
            int hs = h + r - 1;
            float v = 0.f;
            if (hs >= 0 && hs < HH && wp >= 0 && wp < WW)
                v = F[(size_t)(c0 + ic) * NPIX + hs * WW + wp];
            sIn[idx] = v;
        }
        __syncthreads();
        if (tid < WW) {
#pragma unroll
            for (int ic = 0; ic < 8; ic++) {
                const float* row = &sIn[ic * 366];
                float i00 = row[tid], i01 = row[tid + 1], i02 = row[tid + 2];
                float i10 = row[122 + tid], i11 = row[123 + tid], i12 = row[124 + tid];
                float i20 = row[244 + tid], i21 = row[245 + tid], i22 = row[246 + tid];
#pragma unroll
                for (int oc = 0; oc < 8; oc++) {
                    const float* w = &Wt[((size_t)(oc0 + oc) * CIN + (c0 + ic)) * 9];
                    acc[oc] += i00 * w[0] + i01 * w[1] + i02 * w[2]
                             + i10 * w[3] + i11 * w[4] + i12 * w[5]
                             + i20 * w[6] + i21 * w[7] + i22 * w[8];
                }
            }
        }
    }
    if (tid < WW) {
#pragma unroll
        for (int oc = 0; oc < 8; oc++) {
            float v = acc[oc] + Bs[oc0 + oc];
            out[(size_t)(oc0 + oc) * NPIX + h * WW + tid] = fmaxf(v, 0.f);
        }
    }
}

// ---------------- 1x1 heads (cls 18ch + bbox 36ch) ----------------
// grid (54, 76), block 128 (120 active lanes = w)
__global__ __launch_bounds__(128) void heads1x1_kernel(
    const float* __restrict__ rpn,
    const float* __restrict__ cw, const float* __restrict__ cb,
    const float* __restrict__ bw, const float* __restrict__ bb,
    float* __restrict__ cls_s, float* __restrict__ bbox_p) {
    int oc = blockIdx.x;
    int h = blockIdx.y;
    int w = threadIdx.x;
    if (w >= WW) return;
    const float* wv;
    float bias;
    float* out;
    if (oc < 18) { wv = cw + (size_t)oc * CMID; bias = cb[oc]; out = cls_s + (size_t)oc * NPIX; }
    else { wv = bw + (size_t)(oc - 18) * CMID; bias = bb[oc - 18]; out = bbox_p + (size_t)(oc - 18) * NPIX; }
    int pix = h * WW + w;
    float acc = 0.f;
    for (int c = 0; c < CMID; c += 8) {
#pragma unroll
        for (int u = 0; u < 8; u++)
            acc += rpn[(size_t)(c + u) * NPIX + pix] * wv[c + u];
    }
    out[pix] = acc + bias;
}

// ---------------- decode: fg keys + boxes ----------------
__global__ void decode_kernel(const float* __restrict__ cls_s, const float* __restrict__ bbox_p,
                              const float* __restrict__ anchors,
                              unsigned int* __restrict__ keys, float* __restrict__ boxes) {
    int i = blockIdx.x * 256 + threadIdx.x;
    if (i >= NANCH) return;
    int pix = i / AA;
    int a = i - pix * AA;
    float s0 = cls_s[(size_t)a * NPIX + pix];
    float s1 = cls_s[(size_t)(AA + a) * NPIX + pix];
    float d = s1 - s0;  // monotone with fg prob
    unsigned int u = __float_as_uint(d);
    keys[i] = (u & 0x80000000u) ? ~u : (u | 0x80000000u);

    float dx = bbox_p[(size_t)(4 * a + 0) * NPIX + pix];
    float dy = bbox_p[(size_t)(4 * a + 1) * NPIX + pix];
    float dw = bbox_p[(size_t)(4 * a + 2) * NPIX + pix];
    float dh = bbox_p[(size_t)(4 * a + 3) * NPIX + pix];
    float ax1 = anchors[(size_t)i * 4 + 0];
    float ay1 = anchors[(size_t)i * 4 + 1];
    float ax2 = anchors[(size_t)i * 4 + 2];
    float ay2 = anchors[(size_t)i * 4 + 3];
    float aw = ax2 - ax1 + 1.f;
    float ah = ay2 - ay1 + 1.f;
    float acx = ax1 + 0.5f * aw;
    float acy = ay1 + 0.5f * ah;
    float pcx = dx * aw + acx;
    float pcy = dy * ah + acy;
    float pw = __expf(dw) * aw;
    float ph = __expf(dh) * ah;
    const float XMAX = 16.f * WW - 1.f;  // 1919
    const float YMAX = 16.f * HH - 1.f;  // 1215
    boxes[(size_t)i * 4 + 0] = fminf(fmaxf(pcx - 0.5f * pw, 0.f), XMAX);
    boxes[(size_t)i * 4 + 1] = fminf(fmaxf(pcy - 0.5f * ph, 0.f), YMAX);
    boxes[(size_t)i * 4 + 2] = fminf(fmaxf(pcx + 0.5f * pw, 0.f), XMAX);
    boxes[(size_t)i * 4 + 3] = fminf(fmaxf(pcy + 0.5f * ph, 0.f), YMAX);
}

// ---------------- exact top-k (value desc, index asc on ties) ----------------
__global__ __launch_bounds__(1024) void topk_kernel(const unsigned int* __restrict__ keys,
                                                    int* __restrict__ top_idx) {
    const int N = NANCH, K = TOPN;
    __shared__ unsigned int s_prefix;
    __shared__ int s_k;
    __shared__ unsigned int hist[256];
    __shared__ int s_ngt, s_neq;
    __shared__ unsigned long long s_sel[512];
    __shared__ int s_eq[1024];
    int tid = threadIdx.x;
    if (tid == 0) { s_prefix = 0u; s_k = K; }
    __syncthreads();

    // byte-wise radix select, digits 3..0
    for (int d = 3; d >= 0; --d) {
        if (tid < 256) hist[tid] = 0u;
        __syncthreads();
        unsigned int pfx = s_prefix;
        unsigned int maskHigh = (d == 3) ? 0u : ~((1u << ((d + 1) * 8)) - 1u);
        int shift = d * 8;
        for (int i = tid; i < N; i += 1024) {
            unsigned int k = keys[i];
            if ((k & maskHigh) == (pfx & maskHigh))
                atomicAdd(&hist[(k >> shift) & 255u], 1u);
        }
        __syncthreads();
        if (tid == 0) {
            int kk = s_k;
            int cum = 0;
            unsigned int sel = 0;
            for (int v = 255; v >= 0; v--) {
                int h = (int)hist[v];
                if (cum + h >= kk) { sel = (unsigned int)v; s_k = kk - cum; break; }
                cum += h;
            }
            s_prefix = pfx | (sel << shift);
        }
        __syncthreads();
    }
    unsigned int T = s_prefix;
    int krem = s_k;  // take krem of the ==T elements (smallest indices)
    if (tid == 0) { s_ngt = 0; s_neq = 0; }
    __syncthreads();
    for (int i = tid; i < N; i += 1024) {
        unsigned int k = keys[i];
        if (k > T) {
            int p = atomicAdd(&s_ngt, 1);
            if (p < 512)
                s_sel[p] = ((unsigned long long)k << 32) | (unsigned int)(~(unsigned int)i);
        } else if (k == T) {
            int p = atomicAdd(&s_neq, 1);
            if (p < 1024) s_eq[p] = i;
        }
    }
    __syncthreads();
    int ngt = min(s_ngt, 512);
    int neq = min(s_neq, 1024);
    for (int e = tid; e < neq; e += 1024) {
        int idx = s_eq[e];
        int rank = 0;
        for (int j = 0; j < neq; j++)
            if (s_eq[j] < idx) rank++;
        if (rank < krem && ngt + rank < 512)
            s_sel[ngt + rank] = ((unsigned long long)T << 32) | (unsigned int)(~(unsigned int)idx);
    }
    __syncthreads();
    for (int p = K + tid; p < 512; p += 1024) s_sel[p] = 0ULL;
    __syncthreads();
    // bitonic ascending sort of 512 combined keys
    for (unsigned int k2 = 2; k2 <= 512; k2 <<= 1) {
        for (unsigned int j = k2 >> 1; j > 0; j >>= 1) {
            if (tid < 512) {
                int i = tid;
                int ixj = i ^ (int)j;
                if (ixj > i) {
                    unsigned long long a = s_sel[i], c = s_sel[ixj];
                    bool up = ((i & k2) == 0);
                    if (up ? (a > c) : (a < c)) { s_sel[i] = c; s_sel[ixj] = a; }
                }
            }
            __syncthreads();
        }
    }
    if (tid < K)
        top_idx[tid] = (int)(~(unsigned int)(s_sel[511 - tid] & 0xFFFFFFFFull));
}

// ---------------- roi align -> pooled bf16, layout (n, q, c) ----------------
__global__ __launch_bounds__(256) void roialign_kernel(
    const float* __restrict__ F, const float* __restrict__ boxes,
    const int* __restrict__ top_idx, unsigned short* __restrict__ pooled) {
    int n = blockIdx.x;   // 300
    int q = blockIdx.y;   // 49
    int ph = q / 7, pw = q - ph * 7;
    int bi = top_idx[n];
    float x1 = boxes[(size_t)bi * 4 + 0] * (1.f / 16.f);
    float y1 = boxes[(size_t)bi * 4 + 1] * (1.f / 16.f);
    float x2 = boxes[(size_t)bi * 4 + 2] * (1.f / 16.f);
    float y2 = boxes[(size_t)bi * 4 + 3] * (1.f / 16.f);
    float gx = (pw + 0.5f) / 7.f;
    float gy = (ph + 0.5f) / 7.f;
    float xs = fminf(fmaxf(x1 + (x2 - x1) * gx, 0.f), (float)(WW - 1));
    float ys = fminf(fmaxf(y1 + (y2 - y1) * gy, 0.f), (float)(HH - 1));
    float x0f = floorf(xs), y0f = floorf(ys);
    int x0 = (int)x0f, y0 = (int)y0f;
    int x1i = min(x0 + 1, WW - 1);
    int y1i = min(y0 + 1, HH - 1);
    float wx = xs - x0f, wy = ys - y0f;
    float w00 = (1.f - wy) * (1.f - wx), w01 = (1.f - wy) * wx;
    float w10 = wy * (1.f - wx), w11 = wy * wx;
    int o00 = y0 * WW + x0, o01 = y0 * WW + x1i, o10 = y1i * WW + x0, o11 = y1i * WW + x1i;
    unsigned short* dst = pooled + (size_t)n * KFC + (size_t)q * CIN;
    for (int c = threadIdx.x; c < CIN; c += 256) {
        const float* Fc = F + (size_t)c * NPIX;
        float v = w00 * Fc[o00] + w01 * Fc[o01] + w10 * Fc[o10] + w11 * Fc[o11];
        dst[c] = f2bf(v);
    }
}

// ---------------- FC GEMM: fc7 += pooled(300x50176 bf16) @ fc_w ----------------
// grid (32, 5, 8): 64-col tiles, 64-row tiles, split-K 8. block 256, 4x4/thread.
__global__ __launch_bounds__(256) void fc_gemm_kernel(
    const unsigned short* __restrict__ pooled, const float* __restrict__ fc_w,
    float* __restrict__ fc7) {
    __shared__ __align__(16) float As[16][64];
    __shared__ __align__(16) float Ws[16][64];
    int tid = threadIdx.x;
    int jBase = blockIdx.x * 64;
    int mBase = blockIdx.y * 64;
    int kz = blockIdx.z;
    int tx = tid & 15, ty = tid >> 4;
    float acc[4][4];
#pragma unroll
    for (int i = 0; i < 4; i++)
#pragma unroll
        for (int j = 0; j < 4; j++) acc[i][j] = 0.f;

    int am = tid >> 2;
    int ak0 = (tid & 3) * 4;
    int wk = tid >> 4;
    int wj = (tid & 15) * 4;
    int an = mBase + am;

    const int kEnd = kz * 6272 + 6272;
    for (int kb = kz * 6272; kb < kEnd; kb += 16) {
        float a0 = 0.f, a1 = 0.f, a2 = 0.f, a3 = 0.f;
        if (an < TOPN) {
            ushort4 av = *(const ushort4*)(pooled + (size_t)an * KFC + kb + ak0);
            a0 = bf2f(av.x); a1 = bf2f(av.y); a2 = bf2f(av.z); a3 = bf2f(av.w);
        }
        int kp = kb + wk;
        int c = kp & 1023, q = kp >> 10;
        float4 wv = *(const float4*)(fc_w + (size_t)(c * 49 + q) * FCDIM + jBase + wj);
        __syncthreads();
        As[ak0 + 0][am] = a0; As[ak0 + 1][am] = a1;
        As[ak0 + 2][am] = a2; As[ak0 + 3][am] = a3;
        *(float4*)&Ws[wk][wj] = wv;
        __syncthreads();
#pragma unroll
        for (int kk = 0; kk < 16; kk++) {
            float4 a = *(const float4*)&As[kk][ty * 4];
            float4 b = *(const float4*)&Ws[kk][tx * 4];
            float av_[4] = {a.x, a.y, a.z, a.w};
            float bv_[4] = {b.x, b.y, b.z, b.w};
#pragma unroll
            for (int i = 0; i < 4; i++)
#pragma unroll
                for (int j = 0; j < 4; j++) acc[i][j] += av_[i] * bv_[j];
        }
    }
#pragma unroll
    for (int i = 0; i < 4; i++) {
        int n = mBase + ty * 4 + i;
        if (n < TOPN) {
#pragma unroll
            for (int j = 0; j < 4; j++)
                atomicAdd(&fc7[(size_t)n * FCDIM + jBase + tx * 4 + j], acc[i][j]);
        }
    }
}

// ---------------- fc7 bias + relu ----------------
__global__ void bias_relu_kernel(float* __restrict__ fc7, const float* __restrict__ fc_b) {
    int i = blockIdx.x * 256 + threadIdx.x;
    if (i < TOPN * FCDIM)
        fc7[i] = fmaxf(fc7[i] + fc_b[i & (FCDIM - 1)], 0.f);
}

// ---------------- head GEMMs: cls_score (300x21), bbox_pred (300x84) ----------------
__global__ __launch_bounds__(128) void head_gemm_kernel(
    const float* __restrict__ fc7,
    const float* __restrict__ cw, const float* __restrict__ cb,
    const float* __restrict__ bw, const float* __restrict__ bb,
    float* __restrict__ cls_score, float* __restrict__ bbox_pred) {
    int n = blockIdx.x;
    __shared__ float row[FCDIM];
    for (int k = threadIdx.x; k < FCDIM; k += 128) row[k] = fc7[(size_t)n * FCDIM + k];
    __syncthreads();
    int t = threadIdx.x;
    if (t < 21) {
        float acc = 0.f;
        for (int k = 0; k < FCDIM; k += 4) {
#pragma unroll
            for (int u = 0; u < 4; u++) acc += row[k + u] * cw[(size_t)(k + u) * 21 + t];
        }
        cls_score[n * 21 + t] = acc + cb[t];
    } else if (t < 105) {
        int oc = t - 21;
        float acc = 0.f;
        for (int k = 0; k < FCDIM; k += 4) {
#pragma unroll
            for (int u = 0; u < 4; u++) acc += row[k + u] * bw[(size_t)(k + u) * 84 + oc];
        }
        bbox_pred[n * 84 + oc] = acc + bb[oc];
    }
}

// ---------------- losses ----------------
__device__ __forceinline__ void block_atomic_acc(float v, float* dst) {
    for (int o = 32; o > 0; o >>= 1) v += __shfl_down(v, o);
    if ((threadIdx.x & 63) == 0) atomicAdd(dst, v);
}

__global__ void loss_rpn_ce_kernel(const float* __restrict__ cls_s,
                                   const int* __restrict__ labels, float* __restrict__ acc) {
    int i = blockIdx.x * 256 + threadIdx.x;
    float ce = 0.f, cnt = 0.f;
    if (i < NANCH) {
        int lab = labels[i];
        if (lab != -1) {
            int a = i / NPIX, pix = i - a * NPIX;
            float s0 = cls_s[(size_t)a * NPIX + pix];
            float s1 = cls_s[(size_t)(AA + a) * NPIX + pix];
            float m = fmaxf(s0, s1);
            float lse = m + logf(expf(s0 - m) + expf(s1 - m));
            ce = lse - (lab ? s1 : s0);
            cnt = 1.f;
        }
    }
    block_atomic_acc(ce, &acc[0]);
    block_atomic_acc(cnt, &acc[1]);
}

__global__ void loss_rpn_bbox_kernel(const float* __restrict__ bbox_p,
                                     const float* __restrict__ tgt,
                                     const float* __restrict__ biw,
                                     const float* __restrict__ bow, float* __restrict__ acc) {
    int e = blockIdx.x * 256 + threadIdx.x;
    float contrib = 0.f;
    if (e < NPIX * 36) {
        int pix = e / 36, c = e - pix * 36;
        float pred = bbox_p[(size_t)c * NPIX + pix];
        float d = biw[e] * (pred - tgt[e]);
        float ad = fabsf(d);
        float l = (ad < (1.f / 9.f)) ? d * d * 4.5f : ad - (1.f / 18.f);
        contrib = bow[e] * l;
    }
    block_atomic_acc(contrib, &acc[2]);
}

__global__ void loss_cls_kernel(const float* __restrict__ cls_score,
                                const int* __restrict__ labels, float* __restrict__ acc) {
    int n = blockIdx.x * 256 + threadIdx.x;
    float ce = 0.f;
    if (n < TOPN) {
        const float* lg = cls_score + n * 21;
        float m = lg[0];
        for (int j = 1; j < 21; j++) m = fmaxf(m, lg[j]);
        float s = 0.f;
        for (int j = 0; j < 21; j++) s += expf(lg[j] - m);
        ce = m + logf(s) - lg[labels[n]];
    }
    block_atomic_acc(ce, &acc[3]);
}

__global__ void loss_roi_bbox_kernel(const float* __restrict__ bbox_pred,
                                     const float* __restrict__ tgt,
                                     const float* __restrict__ biw,
                                     const float* __restrict__ bow, float* __restrict__ acc) {
    int e = blockIdx.x * 256 + threadIdx.x;
    float contrib = 0.f;
    if (e < TOPN * 84) {
        float d = biw[e] * (bbox_pred[e] - tgt[e]);
        float ad = fabsf(d);
        float l = (ad < 1.f) ? 0.5f * d * d : ad - 0.5f;
        contrib = bow[e] * l;
    }
    block_atomic_acc(contrib, &acc[4]);
}

__global__ void finalize_kernel(const float* __restrict__ acc, float* __restrict__ out) {
    out[0] = acc[0] / fmaxf(acc[1], 1.f) + acc[2]
           + acc[3] * (1.f / TOPN) + acc[4] * (1.f / TOPN);
}

// ---------------- launch ----------------
extern "C" void kernel_launch(void* const* d_in, const int* in_sizes, int n_in,
                              void* d_out, int out_size, void* d_ws, size_t ws_size,
                              hipStream_t stream) {
    const float* net_conv   = (const float*)d_in[0];
    const float* rpn_w      = (const float*)d_in[1];
    const float* rpn_b      = (const float*)d_in[2];
    const float* rpn_cls_w  = (const float*)d_in[3];
    const float* rpn_cls_b  = (const float*)d_in[4];
    const float* rpn_bbox_w = (const float*)d_in[5];
    const float* rpn_bbox_b = (const float*)d_in[6];
    const float* fc_w       = (const float*)d_in[7];
    const float* fc_b       = (const float*)d_in[8];
    const float* cls_w      = (const float*)d_in[9];
    const float* cls_b      = (const float*)d_in[10];
    const float* bbox_w     = (const float*)d_in[11];
    const float* bbox_b     = (const float*)d_in[12];
    const float* anchors    = (const float*)d_in[13];
    const float* rpn_bt     = (const float*)d_in[14];
    const float* rpn_biw    = (const float*)d_in[15];
    const float* rpn_bow    = (const float*)d_in[16];
    const float* roi_bt     = (const float*)d_in[17];
    const float* roi_biw    = (const float*)d_in[18];
    const float* roi_bow    = (const float*)d_in[19];
    const int* rpn_labels   = (const int*)d_in[20];
    const int* roi_labels   = (const int*)d_in[21];

    char* base = (char*)d_ws;
    float* rpn = (float*)base;                        // 18,677,760 B (dead after heads1x1)
    unsigned short* pooled = (unsigned short*)base;   // 30,105,600 B (overlaps rpn)
    size_t off = 30105600;                            // 256-aligned
    float* cls_s = (float*)(base + off);      off += 656640;
    float* bbox_p = (float*)(base + off);     off += 1313280;
    unsigned int* keys = (unsigned int*)(base + off); off += 328448;
    float* boxes = (float*)(base + off);      off += 1313280;
    int* top_idx = (int*)(base + off);        off += 1280;
    float* cls_score = (float*)(base + off);  off += 25344;
    float* bbox_pred = (float*)(base + off);  off += 100864;
    float* fc7 = (float*)(base + off);        off += 2457600;
    float* accum = (float*)(base + off);      off += 64;   // adjacent to fc7
    float* out = (float*)d_out;

    // zero fc7 (614400) + accum (16) in one pass (contiguous)
    zero_kernel<<<2401, 256, 0, stream>>>(fc7, TOPN * FCDIM + 16);
    conv3x3_kernel<<<dim3(64, 76), 128, 0, stream>>>(net_conv, rpn_w, rpn_b, rpn);
    heads1x1_kernel<<<dim3(54, 76), 128, 0, stream>>>(rpn, rpn_cls_w, rpn_cls_b,
                                                      rpn_bbox_w, rpn_bbox_b, cls_s, bbox_p);
    decode_kernel<<<(NANCH + 255) / 256, 256, 0, stream>>>(cls_s, bbox_p, anchors, keys, boxes);
    topk_kernel<<<1, 1024, 0, stream>>>(keys, top_idx);
    roialign_kernel<<<dim3(300, 49), 256, 0, stream>>>(net_conv, boxes, top_idx, pooled);
    fc_gemm_kernel<<<dim3(32, 5, 8), 256, 0, stream>>>(pooled, fc_w, fc7);
    bias_relu_kernel<<<(TOPN * FCDIM + 255) / 256, 256, 0, stream>>>(fc7, fc_b);
    head_gemm_kernel<<<300, 128, 0, stream>>>(fc7, cls_w, cls_b, bbox_w, bbox_b,
                                              cls_score, bbox_pred);
    loss_rpn_ce_kernel<<<(NANCH + 255) / 256, 256, 0, stream>>>(cls_s, rpn_labels, accum);
    loss_rpn_bbox_kernel<<<(NPIX * 36 + 255) / 256, 256, 0, stream>>>(bbox_p, rpn_bt,
                                                                      rpn_biw, rpn_bow, accum);
    loss_cls_kernel<<<2, 256, 0, stream>>>(cls_score, roi_labels, accum);
    loss_roi_bbox_kernel<<<(TOPN * 84 + 255) / 256, 256, 0, stream>>>(bbox_pred, roi_bt,
                                                                      roi_biw, roi_bow, accum);
    finalize_kernel<<<1, 1, 0, stream>>>(accum, out);
}

// Round 2
// 2319.171 us; speedup vs baseline: 5.0563x; 5.0563x over previous
//
#include <hip/hip_runtime.h>
#include <cstddef>

#define HH 76
#define WW 120
#define NPIX (HH*WW)          // 9120
#define AA 9
#define NANCH (NPIX*AA)       // 82080
#define TOPN 300
#define CIN 1024
#define CMID 512
#define FCDIM 2048
#define KFC (CIN*49)          // 50176
#define PW 128
#define PROWS (78*128)        // 9984 padded pixel rows
#define FPIX_ROWS (PROWS + 8) // slack for overreads (max row 9985)

typedef __attribute__((ext_vector_type(8))) short short8;
typedef __attribute__((ext_vector_type(4))) float f32x4;

__device__ __forceinline__ float bf2f(unsigned short h) {
    return __uint_as_float(((unsigned int)h) << 16);
}
__device__ __forceinline__ unsigned short f2bf(float f) {
    unsigned int u = __float_as_uint(f);
    unsigned int r = (u + 0x7FFFu + ((u >> 16) & 1u)) >> 16;
    return (unsigned short)r;
}

// ---------------- zero init ----------------
__global__ void zero_kernel(float* __restrict__ p, int n) {
    int i = blockIdx.x * 256 + threadIdx.x;
    if (i < n) p[i] = 0.f;
}
__global__ void zero4_kernel(float4* __restrict__ p, int n4) {
    int i = blockIdx.x * 256 + threadIdx.x;
    if (i < n4) p[i] = make_float4(0.f, 0.f, 0.f, 0.f);
}

// ---------------- Fpix fill: [ic][px] fp32 -> [padded px][ic] bf16 ----------------
// grid (143, 16), block 256: 64px x 64ic tile via LDS transpose
__global__ __launch_bounds__(256) void fpix_fill_kernel(const float* __restrict__ F,
                                                        unsigned short* __restrict__ Fpix) {
    __shared__ float s[64][65];
    int px0 = blockIdx.x * 64, ic0 = blockIdx.y * 64;
    int t = threadIdx.x;
#pragma unroll 4
    for (int i = 0; i < 16; i++) {
        int ic = (t >> 6) + i * 4;
        int px = px0 + (t & 63);
        float v = (px < NPIX) ? F[(size_t)(ic0 + ic) * NPIX + px] : 0.f;
        s[t & 63][ic] = v;
    }
    __syncthreads();
    int pxl = t >> 2;
    int px = px0 + pxl;
    if (px < NPIX) {
        int h = px / 120, w = px - h * 120;
        size_t prow = (size_t)(h + 1) * PW + (w + 1);
        unsigned short* dst = Fpix + prow * 1024 + ic0 + (t & 3) * 16;
#pragma unroll
        for (int u = 0; u < 16; u++) dst[u] = f2bf(s[pxl][(t & 3) * 16 + u]);
    }
}

// ---------------- Wb fill: [oc][ic][3][3] fp32 -> [tap][oc][ic] bf16 ----------------
__global__ void wb_fill_kernel(const float* __restrict__ Wsrc, unsigned short* __restrict__ Wb) {
    int idx = blockIdx.x * 256 + threadIdx.x;
    if (idx >= 9 * 512 * 1024) return;
    int t = idx >> 19;
    int r = idx & 524287;  // oc*1024+ic
    Wb[idx] = f2bf(Wsrc[(size_t)r * 9 + t]);
}

// ---------------- conv 3x3 via MFMA implicit GEMM ----------------
// grid (8 oc-tiles, 76 h), block 256 (4 waves). Block tile: 128 px x 64 oc.
// Wave tile: 64 px x 32 oc = 4x2 subtiles of 16x16, K-chunks of 32 (9 taps x 32).
__global__ __launch_bounds__(256) void conv_mfma_kernel(
    const unsigned short* __restrict__ Fpix,  // [FPIX_ROWS][1024] bf16
    const unsigned short* __restrict__ Wb,    // [9][512][1024] bf16
    const float* __restrict__ Bs,
    unsigned short* __restrict__ out) {       // rpn bf16 [512][9120]
    __shared__ __align__(16) unsigned short As[4 * 128 * 8];  // chunk id = quad*128+px
    __shared__ __align__(16) unsigned short Ws[4 * 64 * 8];   // chunk id = quad*64+oc
    const int tid = threadIdx.x;
    const int oct = blockIdx.x;
    const int h = blockIdx.y;
    const int lane = tid & 63, wv = tid >> 6;
    const int lane16 = lane & 15, quad = lane >> 4;
    const int wave_px = (wv & 1) * 64, wave_oc = (wv >> 1) * 32;

    // staging mapping: A chunks tid(+0/ +256) -> (quad, px); B chunk tid -> (quad, oc)
    const int a_px = tid & 127;
    const int aq0 = tid >> 7;   // 0/1; second load uses aq0+2
    const int b_oc = tid & 63;
    const int bq = tid >> 6;

    f32x4 acc[4][2];
#pragma unroll
    for (int mi = 0; mi < 4; mi++)
#pragma unroll
        for (int ni = 0; ni < 2; ni++) acc[mi][ni] = (f32x4){0.f, 0.f, 0.f, 0.f};

    short8 ra0, ra1, rb;
    {   // preload chunk 0: tap 0 (dh=0,dw=0), ic0=0
        const unsigned short* arow = Fpix + (size_t)((h + 0) * PW + a_px + 0) * 1024 + 0;
        ra0 = *(const short8*)(arow + aq0 * 8);
        ra1 = *(const short8*)(arow + (aq0 + 2) * 8);
        rb = *(const short8*)(Wb + (size_t)((0 * 512 + oct * 64 + b_oc)) * 1024 + 0 + bq * 8);
    }
    for (int c = 0; c < 288; ++c) {
        __syncthreads();
        *(short8*)&As[(aq0 * 128 + a_px) * 8] = ra0;
        *(short8*)&As[((aq0 + 2) * 128 + a_px) * 8] = ra1;
        *(short8*)&Ws[(bq * 64 + b_oc) * 8] = rb;
        if (c + 1 < 288) {
            int cn = c + 1;
            int tap = cn >> 5;
            int ic0 = (cn & 31) << 5;
            int dh = tap / 3, dw = tap - dh * 3;
            const unsigned short* arow =
                Fpix + (size_t)((h + dh) * PW + a_px + dw) * 1024 + ic0;
            ra0 = *(const short8*)(arow + aq0 * 8);
            ra1 = *(const short8*)(arow + (aq0 + 2) * 8);
            rb = *(const short8*)(Wb + (size_t)((tap * 512 + oct * 64 + b_oc)) * 1024 + ic0 + bq * 8);
        }
        __syncthreads();
        short8 af[4], bf[2];
#pragma unroll
        for (int mi = 0; mi < 4; mi++)
            af[mi] = *(const short8*)&As[(quad * 128 + wave_px + mi * 16 + lane16) * 8];
#pragma unroll
        for (int ni = 0; ni < 2; ni++)
            bf[ni] = *(const short8*)&Ws[(quad * 64 + wave_oc + ni * 16 + lane16) * 8];
#pragma unroll
        for (int mi = 0; mi < 4; mi++)
#pragma unroll
            for (int ni = 0; ni < 2; ni++)
                acc[mi][ni] = __builtin_amdgcn_mfma_f32_16x16x32_bf16(af[mi], bf[ni],
                                                                     acc[mi][ni], 0, 0, 0);
    }
    // epilogue: D[row=px=quad*4+r][col=oc=lane16]
#pragma unroll
    for (int ni = 0; ni < 2; ni++) {
        int oc = wave_oc + ni * 16 + lane16;
        float bias = Bs[oct * 64 + oc];
        unsigned short* orow = out + (size_t)(oct * 64 + oc) * NPIX + h * 120;
#pragma unroll
        for (int mi = 0; mi < 4; mi++) {
#pragma unroll
            for (int r = 0; r < 4; r++) {
                int px = wave_px + mi * 16 + quad * 4 + r;
                if (px < 120) orow[px] = f2bf(fmaxf(acc[mi][ni][r] + bias, 0.f));
            }
        }
    }
}

// ---------------- 1x1 heads (cls 18ch + bbox 36ch), bf16 rpn input ----------------
__global__ __launch_bounds__(128) void heads1x1_kernel(
    const unsigned short* __restrict__ rpn,
    const float* __restrict__ cw, const float* __restrict__ cb,
    const float* __restrict__ bw, const float* __restrict__ bb,
    float* __restrict__ cls_s, float* __restrict__ bbox_p) {
    int oc = blockIdx.x;
    int h = blockIdx.y;
    int w = threadIdx.x;
    if (w >= WW) return;
    const float* wv;
    float bias;
    float* out;
    if (oc < 18) { wv = cw + (size_t)oc * CMID; bias = cb[oc]; out = cls_s + (size_t)oc * NPIX; }
    else { wv = bw + (size_t)(oc - 18) * CMID; bias = bb[oc - 18]; out = bbox_p + (size_t)(oc - 18) * NPIX; }
    int pix = h * WW + w;
    float acc = 0.f;
    for (int c = 0; c < CMID; c += 8) {
#pragma unroll
        for (int u = 0; u < 8; u++)
            acc += bf2f(rpn[(size_t)(c + u) * NPIX + pix]) * wv[c + u];
    }
    out[pix] = acc + bias;
}

// ---------------- decode: fg keys + boxes ----------------
__global__ void decode_kernel(const float* __restrict__ cls_s, const float* __restrict__ bbox_p,
                              const float* __restrict__ anchors,
                              unsigned int* __restrict__ keys, float* __restrict__ boxes) {
    int i = blockIdx.x * 256 + threadIdx.x;
    if (i >= NANCH) return;
    int pix = i / AA;
    int a = i - pix * AA;
    float s0 = cls_s[(size_t)a * NPIX + pix];
    float s1 = cls_s[(size_t)(AA + a) * NPIX + pix];
    float d = s1 - s0;
    unsigned int u = __float_as_uint(d);
    keys[i] = (u & 0x80000000u) ? ~u : (u | 0x80000000u);

    float dx = bbox_p[(size_t)(4 * a + 0) * NPIX + pix];
    float dy = bbox_p[(size_t)(4 * a + 1) * NPIX + pix];
    float dw = bbox_p[(size_t)(4 * a + 2) * NPIX + pix];
    float dh = bbox_p[(size_t)(4 * a + 3) * NPIX + pix];
    float ax1 = anchors[(size_t)i * 4 + 0];
    float ay1 = anchors[(size_t)i * 4 + 1];
    float ax2 = anchors[(size_t)i * 4 + 2];
    float ay2 = anchors[(size_t)i * 4 + 3];
    float aw = ax2 - ax1 + 1.f;
    float ah = ay2 - ay1 + 1.f;
    float acx = ax1 + 0.5f * aw;
    float acy = ay1 + 0.5f * ah;
    float pcx = dx * aw + acx;
    float pcy = dy * ah + acy;
    float pw = __expf(dw) * aw;
    float ph = __expf(dh) * ah;
    const float XMAX = 16.f * WW - 1.f;
    const float YMAX = 16.f * HH - 1.f;
    boxes[(size_t)i * 4 + 0] = fminf(fmaxf(pcx - 0.5f * pw, 0.f), XMAX);
    boxes[(size_t)i * 4 + 1] = fminf(fmaxf(pcy - 0.5f * ph, 0.f), YMAX);
    boxes[(size_t)i * 4 + 2] = fminf(fmaxf(pcx + 0.5f * pw, 0.f), XMAX);
    boxes[(size_t)i * 4 + 3] = fminf(fmaxf(pcy + 0.5f * ph, 0.f), YMAX);
}

// ---------------- exact top-k (value desc, index asc on ties) ----------------
__global__ __launch_bounds__(1024) void topk_kernel(const unsigned int* __restrict__ keys,
                                                    int* __restrict__ top_idx) {
    const int N = NANCH, K = TOPN;
    __shared__ unsigned int s_prefix;
    __shared__ int s_k;
    __shared__ unsigned int hist[256];
    __shared__ int s_ngt, s_neq;
    __shared__ unsigned long long s_sel[512];
    __shared__ int s_eq[1024];
    int tid = threadIdx.x;
    if (tid == 0) { s_prefix = 0u; s_k = K; }
    __syncthreads();

    for (int d = 3; d >= 0; --d) {
        if (tid < 256) hist[tid] = 0u;
        __syncthreads();
        unsigned int pfx = s_prefix;
        unsigned int maskHigh = (d == 3) ? 0u : ~((1u << ((d + 1) * 8)) - 1u);
        int shift = d * 8;
        for (int i = tid; i < N; i += 1024) {
            unsigned int k = keys[i];
            if ((k & maskHigh) == (pfx & maskHigh))
                atomicAdd(&hist[(k >> shift) & 255u], 1u);
        }
        __syncthreads();
        if (tid == 0) {
            int kk = s_k;
            int cum = 0;
            unsigned int sel = 0;
            for (int v = 255; v >= 0; v--) {
                int hcnt = (int)hist[v];
                if (cum + hcnt >= kk) { sel = (unsigned int)v; s_k = kk - cum; break; }
                cum += hcnt;
            }
            s_prefix = pfx | (sel << shift);
        }
        __syncthreads();
    }
    unsigned int T = s_prefix;
    int krem = s_k;
    if (tid == 0) { s_ngt = 0; s_neq = 0; }
    __syncthreads();
    for (int i = tid; i < N; i += 1024) {
        unsigned int k = keys[i];
        if (k > T) {
            int p = atomicAdd(&s_ngt, 1);
            if (p < 512)
                s_sel[p] = ((unsigned long long)k << 32) | (unsigned int)(~(unsigned int)i);
        } else if (k == T) {
            int p = atomicAdd(&s_neq, 1);
            if (p < 1024) s_eq[p] = i;
        }
    }
    __syncthreads();
    int ngt = min(s_ngt, 512);
    int neq = min(s_neq, 1024);
    for (int e = tid; e < neq; e += 1024) {
        int idx = s_eq[e];
        int rank = 0;
        for (int j = 0; j < neq; j++)
            if (s_eq[j] < idx) rank++;
        if (rank < krem && ngt + rank < 512)
            s_sel[ngt + rank] = ((unsigned long long)T << 32) | (unsigned int)(~(unsigned int)idx);
    }
    __syncthreads();
    for (int p = K + tid; p < 512; p += 1024) s_sel[p] = 0ULL;
    __syncthreads();
    for (unsigned int k2 = 2; k2 <= 512; k2 <<= 1) {
        for (unsigned int j = k2 >> 1; j > 0; j >>= 1) {
            if (tid < 512) {
                int i = tid;
                int ixj = i ^ (int)j;
                if (ixj > i) {
                    unsigned long long a = s_sel[i], cc = s_sel[ixj];
                    bool up = ((i & k2) == 0);
                    if (up ? (a > cc) : (a < cc)) { s_sel[i] = cc; s_sel[ixj] = a; }
                }
            }
            __syncthreads();
        }
    }
    if (tid < K)
        top_idx[tid] = (int)(~(unsigned int)(s_sel[511 - tid] & 0xFFFFFFFFull));
}

// ---------------- roi align from Fpix (bf16, pixel-major) -> pooled (n,q,c) bf16 ----------------
__global__ __launch_bounds__(256) void roialign_kernel(
    const unsigned short* __restrict__ Fpix, const float* __restrict__ boxes,
    const int* __restrict__ top_idx, unsigned short* __restrict__ pooled) {
    int n = blockIdx.x;
    int q = blockIdx.y;
    int ph = q / 7, pw = q - ph * 7;
    int bi = top_idx[n];
    float x1 = boxes[(size_t)bi * 4 + 0] * (1.f / 16.f);
    float y1 = boxes[(size_t)bi * 4 + 1] * (1.f / 16.f);
    float x2 = boxes[(size_t)bi * 4 + 2] * (1.f / 16.f);
    float y2 = boxes[(size_t)bi * 4 + 3] * (1.f / 16.f);
    float gx = (pw + 0.5f) / 7.f;
    float gy = (ph + 0.5f) / 7.f;
    float xs = fminf(fmaxf(x1 + (x2 - x1) * gx, 0.f), (float)(WW - 1));
    float ys = fminf(fmaxf(y1 + (y2 - y1) * gy, 0.f), (float)(HH - 1));
    float x0f = floorf(xs), y0f = floorf(ys);
    int x0 = (int)x0f, y0 = (int)y0f;
    int x1i = min(x0 + 1, WW - 1);
    int y1i = min(y0 + 1, HH - 1);
    float wx = xs - x0f, wy = ys - y0f;
    float w00 = (1.f - wy) * (1.f - wx), w01 = (1.f - wy) * wx;
    float w10 = wy * (1.f - wx), w11 = wy * wx;
    const unsigned short* r00 = Fpix + (size_t)((y0 + 1) * PW + x0 + 1) * 1024;
    const unsigned short* r01 = Fpix + (size_t)((y0 + 1) * PW + x1i + 1) * 1024;
    const unsigned short* r10 = Fpix + (size_t)((y1i + 1) * PW + x0 + 1) * 1024;
    const unsigned short* r11 = Fpix + (size_t)((y1i + 1) * PW + x1i + 1) * 1024;
    unsigned short* dst = pooled + (size_t)n * KFC + (size_t)q * CIN;
    for (int c = threadIdx.x; c < CIN; c += 256) {
        float v = w00 * bf2f(r00[c]) + w01 * bf2f(r01[c])
                + w10 * bf2f(r10[c]) + w11 * bf2f(r11[c]);
        dst[c] = f2bf(v);
    }
}

// ---------------- FC GEMM: fc7 += pooled(300x50176 bf16) @ fc_w ----------------
__global__ __launch_bounds__(256) void fc_gemm_kernel(
    const unsigned short* __restrict__ pooled, const float* __restrict__ fc_w,
    float* __restrict__ fc7) {
    __shared__ __align__(16) float As[16][64];
    __shared__ __align__(16) float Ws[16][64];
    int tid = threadIdx.x;
    int jBase = blockIdx.x * 64;
    int mBase = blockIdx.y * 64;
    int kz = blockIdx.z;
    int tx = tid & 15, ty = tid >> 4;
    float acc[4][4];
#pragma unroll
    for (int i = 0; i < 4; i++)
#pragma unroll
        for (int j = 0; j < 4; j++) acc[i][j] = 0.f;

    int am = tid >> 2;
    int ak0 = (tid & 3) * 4;
    int wk = tid >> 4;
    int wj = (tid & 15) * 4;
    int an = mBase + am;

    const int kEnd = kz * 6272 + 6272;
    for (int kb = kz * 6272; kb < kEnd; kb += 16) {
        float a0 = 0.f, a1 = 0.f, a2 = 0.f, a3 = 0.f;
        if (an < TOPN) {
            ushort4 av = *(const ushort4*)(pooled + (size_t)an * KFC + kb + ak0);
            a0 = bf2f(av.x); a1 = bf2f(av.y); a2 = bf2f(av.z); a3 = bf2f(av.w);
        }
        int kp = kb + wk;
        int c = kp & 1023, q = kp >> 10;
        float4 wv = *(const float4*)(fc_w + (size_t)(c * 49 + q) * FCDIM + jBase + wj);
        __syncthreads();
        As[ak0 + 0][am] = a0; As[ak0 + 1][am] = a1;
        As[ak0 + 2][am] = a2; As[ak0 + 3][am] = a3;
        *(float4*)&Ws[wk][wj] = wv;
        __syncthreads();
#pragma unroll
        for (int kk = 0; kk < 16; kk++) {
            float4 a = *(const float4*)&As[kk][ty * 4];
            float4 b = *(const float4*)&Ws[kk][tx * 4];
            float av_[4] = {a.x, a.y, a.z, a.w};
            float bv_[4] = {b.x, b.y, b.z, b.w};
#pragma unroll
            for (int i = 0; i < 4; i++)
#pragma unroll
                for (int j = 0; j < 4; j++) acc[i][j] += av_[i] * bv_[j];
        }
    }
#pragma unroll
    for (int i = 0; i < 4; i++) {
        int n = mBase + ty * 4 + i;
        if (n < TOPN) {
#pragma unroll
            for (int j = 0; j < 4; j++)
                atomicAdd(&fc7[(size_t)n * FCDIM + jBase + tx * 4 + j], acc[i][j]);
        }
    }
}

// ---------------- fc7 bias + relu ----------------
__global__ void bias_relu_kernel(float* __restrict__ fc7, const float* __restrict__ fc_b) {
    int i = blockIdx.x * 256 + threadIdx.x;
    if (i < TOPN * FCDIM)
        fc7[i] = fmaxf(fc7[i] + fc_b[i & (FCDIM - 1)], 0.f);
}

// ---------------- head GEMMs ----------------
__global__ __launch_bounds__(128) void head_gemm_kernel(
    const float* __restrict__ fc7,
    const float* __restrict__ cw, const float* __restrict__ cb,
    const float* __restrict__ bw, const float* __restrict__ bb,
    float* __restrict__ cls_score, float* __restrict__ bbox_pred) {
    int n = blockIdx.x;
    __shared__ float row[FCDIM];
    for (int k = threadIdx.x; k < FCDIM; k += 128) row[k] = fc7[(size_t)n * FCDIM + k];
    __syncthreads();
    int t = threadIdx.x;
    if (t < 21) {
        float acc = 0.f;
        for (int k = 0; k < FCDIM; k += 4) {
#pragma unroll
            for (int u = 0; u < 4; u++) acc += row[k + u] * cw[(size_t)(k + u) * 21 + t];
        }
        cls_score[n * 21 + t] = acc + cb[t];
    } else if (t < 105) {
        int oc = t - 21;
        float acc = 0.f;
        for (int k = 0; k < FCDIM; k += 4) {
#pragma unroll
            for (int u = 0; u < 4; u++) acc += row[k + u] * bw[(size_t)(k + u) * 84 + oc];
        }
        bbox_pred[n * 84 + oc] = acc + bb[oc];
    }
}

// ---------------- losses ----------------
__device__ __forceinline__ void block_atomic_acc(float v, float* dst) {
    for (int o = 32; o > 0; o >>= 1) v += __shfl_down(v, o);
    if ((threadIdx.x & 63) == 0) atomicAdd(dst, v);
}

__global__ void loss_rpn_ce_kernel(const float* __restrict__ cls_s,
                                   const int* __restrict__ labels, float* __restrict__ acc) {
    int i = blockIdx.x * 256 + threadIdx.x;
    float ce = 0.f, cnt = 0.f;
    if (i < NANCH) {
        int lab = labels[i];
        if (lab != -1) {
            int a = i / NPIX, pix = i - a * NPIX;
            float s0 = cls_s[(size_t)a * NPIX + pix];
            float s1 = cls_s[(size_t)(AA + a) * NPIX + pix];
            float m = fmaxf(s0, s1);
            float lse = m + logf(expf(s0 - m) + expf(s1 - m));
            ce = lse - (lab ? s1 : s0);
            cnt = 1.f;
        }
    }
    block_atomic_acc(ce, &acc[0]);
    block_atomic_acc(cnt, &acc[1]);
}

__global__ void loss_rpn_bbox_kernel(const float* __restrict__ bbox_p,
                                     const float* __restrict__ tgt,
                                     const float* __restrict__ biw,
                                     const float* __restrict__ bow, float* __restrict__ acc) {
    int e = blockIdx.x * 256 + threadIdx.x;
    float contrib = 0.f;
    if (e < NPIX * 36) {
        int pix = e / 36, c = e - pix * 36;
        float pred = bbox_p[(size_t)c * NPIX + pix];
        float d = biw[e] * (pred - tgt[e]);
        float ad = fabsf(d);
        float l = (ad < (1.f / 9.f)) ? d * d * 4.5f : ad - (1.f / 18.f);
        contrib = bow[e] * l;
    }
    block_atomic_acc(contrib, &acc[2]);
}

__global__ void loss_cls_kernel(const float* __restrict__ cls_score,
                                const int* __restrict__ labels, float* __restrict__ acc) {
    int n = blockIdx.x * 256 + threadIdx.x;
    float ce = 0.f;
    if (n < TOPN) {
        const float* lg = cls_score + n * 21;
        float m = lg[0];
        for (int j = 1; j < 21; j++) m = fmaxf(m, lg[j]);
        float s = 0.f;
        for (int j = 0; j < 21; j++) s += expf(lg[j] - m);
        ce = m + logf(s) - lg[labels[n]];
    }
    block_atomic_acc(ce, &acc[3]);
}

__global__ void loss_roi_bbox_kernel(const float* __restrict__ bbox_pred,
                                     const float* __restrict__ tgt,
                                     const float* __restrict__ biw,
                                     const float* __restrict__ bow, float* __restrict__ acc) {
    int e = blockIdx.x * 256 + threadIdx.x;
    float contrib = 0.f;
    if (e < TOPN * 84) {
        float d = biw[e] * (bbox_pred[e] - tgt[e]);
        float ad = fabsf(d);
        float l = (ad < 1.f) ? 0.5f * d * d : ad - 0.5f;
        contrib = bow[e] * l;
    }
    block_atomic_acc(contrib, &acc[4]);
}

__global__ void finalize_kernel(const float* __restrict__ acc, float* __restrict__ out) {
    out[0] = acc[0] / fmaxf(acc[1], 1.f) + acc[2]
           + acc[3] * (1.f / TOPN) + acc[4] * (1.f / TOPN);
}

// ---------------- launch ----------------
extern "C" void kernel_launch(void* const* d_in, const int* in_sizes, int n_in,
                              void* d_out, int out_size, void* d_ws, size_t ws_size,
                              hipStream_t stream) {
    const float* net_conv   = (const float*)d_in[0];
    const float* rpn_w      = (const float*)d_in[1];
    const float* rpn_b      = (const float*)d_in[2];
    const float* rpn_cls_w  = (const float*)d_in[3];
    const float* rpn_cls_b  = (const float*)d_in[4];
    const float* rpn_bbox_w = (const float*)d_in[5];
    const float* rpn_bbox_b = (const float*)d_in[6];
    const float* fc_w       = (const float*)d_in[7];
    const float* fc_b       = (const float*)d_in[8];
    const float* cls_w      = (const float*)d_in[9];
    const float* cls_b      = (const float*)d_in[10];
    const float* bbox_w     = (const float*)d_in[11];
    const float* bbox_b     = (const float*)d_in[12];
    const float* anchors    = (const float*)d_in[13];
    const float* rpn_bt     = (const float*)d_in[14];
    const float* rpn_biw    = (const float*)d_in[15];
    const float* rpn_bow    = (const float*)d_in[16];
    const float* roi_bt     = (const float*)d_in[17];
    const float* roi_biw    = (const float*)d_in[18];
    const float* roi_bow    = (const float*)d_in[19];
    const int* rpn_labels   = (const int*)d_in[20];
    const int* roi_labels   = (const int*)d_in[21];

    char* base = (char*)d_ws;
    // [0, 20463616): Fpix bf16 (FPIX_ROWS x 1024) — live until roialign done
    unsigned short* Fpix = (unsigned short*)base;
    const size_t FPIX_BYTES = (size_t)FPIX_ROWS * 1024 * 2;  // 20,463,616
    // [20463616, 29900800): Wb bf16 — dead after conv
    unsigned short* Wb = (unsigned short*)(base + FPIX_BYTES);
    // [29900800, 39239680): rpn bf16 — dead after heads1x1
    unsigned short* rpn = (unsigned short*)(base + 29900800);
    // pooled overlays Wb+rpn region: [20463616, 50569216)
    unsigned short* pooled = (unsigned short*)(base + FPIX_BYTES);
    size_t off = 50569216;
    float* cls_s = (float*)(base + off);      off += 656640;
    float* bbox_p = (float*)(base + off);     off += 1313280;
    unsigned int* keys = (unsigned int*)(base + off); off += 328448;
    float* boxes = (float*)(base + off);      off += 1313280;
    int* top_idx = (int*)(base + off);        off += 1280;
    float* cls_score = (float*)(base + off);  off += 25600;
    float* bbox_pred = (float*)(base + off);  off += 100864;
    float* fc7 = (float*)(base + off);        off += 2457600;
    float* accum = (float*)(base + off);      off += 256;
    float* out = (float*)d_out;

    // transforms
    zero4_kernel<<<(int)((FPIX_BYTES / 16 + 255) / 256), 256, 0, stream>>>((float4*)Fpix,
                                                                           (int)(FPIX_BYTES / 16));
    fpix_fill_kernel<<<dim3(143, 16), 256, 0, stream>>>(net_conv, Fpix);
    wb_fill_kernel<<<18432, 256, 0, stream>>>(rpn_w, Wb);
    zero_kernel<<<2401, 256, 0, stream>>>(fc7, TOPN * FCDIM + 16);

    conv_mfma_kernel<<<dim3(8, 76), 256, 0, stream>>>(Fpix, Wb, rpn_b, rpn);
    heads1x1_kernel<<<dim3(54, 76), 128, 0, stream>>>(rpn, rpn_cls_w, rpn_cls_b,
                                                      rpn_bbox_w, rpn_bbox_b, cls_s, bbox_p);
    decode_kernel<<<(NANCH + 255) / 256, 256, 0, stream>>>(cls_s, bbox_p, anchors, keys, boxes);
    topk_kernel<<<1, 1024, 0, stream>>>(keys, top_idx);
    roialign_kernel<<<dim3(300, 49), 256, 0, stream>>>(Fpix, boxes, top_idx, pooled);
    fc_gemm_kernel<<<dim3(32, 5, 8), 256, 0, stream>>>(pooled, fc_w, fc7);
    bias_relu_kernel<<<(TOPN * FCDIM + 255) / 256, 256, 0, stream>>>(fc7, fc_b);
    head_gemm_kernel<<<300, 128, 0, stream>>>(fc7, cls_w, cls_b, bbox_w, bbox_b,
                                              cls_score, bbox_pred);
    loss_rpn_ce_kernel<<<(NANCH + 255) / 256, 256, 0, stream>>>(cls_s, rpn_labels, accum);
    loss_rpn_bbox_kernel<<<(NPIX * 36 + 255) / 256, 256, 0, stream>>>(bbox_p, rpn_bt,
                                                                      rpn_biw, rpn_bow, accum);
    loss_cls_kernel<<<2, 256, 0, stream>>>(cls_score, roi_labels, accum);
    loss_roi_bbox_kernel<<<(TOPN * 84 + 255) / 256, 256, 0, stream>>>(bbox_pred, roi_bt,
                                                                      roi_biw, roi_bow, accum);
    finalize_kernel<<<1, 1, 0, stream>>>(accum, out);
}

// Round 3
// 1477.463 us; speedup vs baseline: 7.9368x; 1.5697x over previous
//
#include <hip/hip_runtime.h>
#include <cstddef>

#define HH 76
#define WW 120
#define NPIX (HH*WW)          // 9120
#define AA 9
#define NANCH (NPIX*AA)       // 82080
#define TOPN 300
#define CIN 1024
#define CMID 512
#define FCDIM 2048
#define KFC (CIN*49)          // 50176
#define PW 128
#define PROWS (78*128)        // 9984 padded pixel rows
#define FPIX_ROWS (PROWS + 8)

typedef __attribute__((ext_vector_type(8))) short short8;
typedef __attribute__((ext_vector_type(4))) float f32x4;

__device__ __forceinline__ float bf2f(unsigned short h) {
    return __uint_as_float(((unsigned int)h) << 16);
}
__device__ __forceinline__ unsigned short f2bf(float f) {
    unsigned int u = __float_as_uint(f);
    unsigned int r = (u + 0x7FFFu + ((u >> 16) & 1u)) >> 16;
    return (unsigned short)r;
}

// ---------------- zero init ----------------
__global__ void zero_kernel(float* __restrict__ p, int n) {
    int i = blockIdx.x * 256 + threadIdx.x;
    if (i < n) p[i] = 0.f;
}
__global__ void zero4_kernel(float4* __restrict__ p, int n4) {
    int i = blockIdx.x * 256 + threadIdx.x;
    if (i < n4) p[i] = make_float4(0.f, 0.f, 0.f, 0.f);
}

// ---------------- Fpix fill: [ic][px] fp32 -> [padded px][ic] bf16 ----------------
__global__ __launch_bounds__(256) void fpix_fill_kernel(const float* __restrict__ F,
                                                        unsigned short* __restrict__ Fpix) {
    __shared__ float s[64][65];
    int px0 = blockIdx.x * 64, ic0 = blockIdx.y * 64;
    int t = threadIdx.x;
#pragma unroll 4
    for (int i = 0; i < 16; i++) {
        int ic = (t >> 6) + i * 4;
        int px = px0 + (t & 63);
        float v = (px < NPIX) ? F[(size_t)(ic0 + ic) * NPIX + px] : 0.f;
        s[t & 63][ic] = v;
    }
    __syncthreads();
    int pxl = t >> 2;
    int px = px0 + pxl;
    if (px < NPIX) {
        int h = px / 120, w = px - h * 120;
        size_t prow = (size_t)(h + 1) * PW + (w + 1);
        unsigned short* dst = Fpix + prow * 1024 + ic0 + (t & 3) * 16;
#pragma unroll
        for (int u = 0; u < 16; u++) dst[u] = f2bf(s[pxl][(t & 3) * 16 + u]);
    }
}

// ---------------- Wb fill: [ocic][9] fp32 -> [tap][ocic] bf16 (LDS transpose) ----------------
__global__ __launch_bounds__(256) void wb_fill_kernel(const float* __restrict__ Wsrc,
                                                      unsigned short* __restrict__ Wb) {
    __shared__ float s[2304];
    int r0 = blockIdx.x * 256;
    int t = threadIdx.x;
    const float4* src4 = (const float4*)(Wsrc + (size_t)r0 * 9);
#pragma unroll
    for (int i = 0; i < 3; i++) {
        int idx = t + 256 * i;
        if (idx < 576) *(float4*)&s[idx * 4] = src4[idx];
    }
    __syncthreads();
#pragma unroll
    for (int tap = 0; tap < 9; tap++)
        Wb[(size_t)tap * 524288 + r0 + t] = f2bf(s[t * 9 + tap]);
}

// ---------------- conv 3x3 via MFMA implicit GEMM -> rpn pixel-major [px][512] ----------------
__global__ __launch_bounds__(256) void conv_mfma_kernel(
    const unsigned short* __restrict__ Fpix,
    const unsigned short* __restrict__ Wb,
    const float* __restrict__ Bs,
    unsigned short* __restrict__ out) {       // [9120][512] bf16
    __shared__ __align__(16) unsigned short As[4 * 128 * 8];
    __shared__ __align__(16) unsigned short Ws[4 * 64 * 8];
    const int tid = threadIdx.x;
    const int oct = blockIdx.x;
    const int h = blockIdx.y;
    const int lane = tid & 63, wv = tid >> 6;
    const int lane16 = lane & 15, quad = lane >> 4;
    const int wave_px = (wv & 1) * 64, wave_oc = (wv >> 1) * 32;

    const int a_px = tid & 127;
    const int aq0 = tid >> 7;
    const int b_oc = tid & 63;
    const int bq = tid >> 6;

    f32x4 acc[4][2];
#pragma unroll
    for (int mi = 0; mi < 4; mi++)
#pragma unroll
        for (int ni = 0; ni < 2; ni++) acc[mi][ni] = (f32x4){0.f, 0.f, 0.f, 0.f};

    short8 ra0, ra1, rb;
    {
        const unsigned short* arow = Fpix + (size_t)((h + 0) * PW + a_px + 0) * 1024 + 0;
        ra0 = *(const short8*)(arow + aq0 * 8);
        ra1 = *(const short8*)(arow + (aq0 + 2) * 8);
        rb = *(const short8*)(Wb + (size_t)((0 * 512 + oct * 64 + b_oc)) * 1024 + 0 + bq * 8);
    }
    for (int c = 0; c < 288; ++c) {
        __syncthreads();
        *(short8*)&As[(aq0 * 128 + a_px) * 8] = ra0;
        *(short8*)&As[((aq0 + 2) * 128 + a_px) * 8] = ra1;
        *(short8*)&Ws[(bq * 64 + b_oc) * 8] = rb;
        if (c + 1 < 288) {
            int cn = c + 1;
            int tap = cn >> 5;
            int ic0 = (cn & 31) << 5;
            int dh = tap / 3, dw = tap - dh * 3;
            const unsigned short* arow =
                Fpix + (size_t)((h + dh) * PW + a_px + dw) * 1024 + ic0;
            ra0 = *(const short8*)(arow + aq0 * 8);
            ra1 = *(const short8*)(arow + (aq0 + 2) * 8);
            rb = *(const short8*)(Wb + (size_t)((tap * 512 + oct * 64 + b_oc)) * 1024 + ic0 + bq * 8);
        }
        __syncthreads();
        short8 af[4], bfr[2];
#pragma unroll
        for (int mi = 0; mi < 4; mi++)
            af[mi] = *(const short8*)&As[(quad * 128 + wave_px + mi * 16 + lane16) * 8];
#pragma unroll
        for (int ni = 0; ni < 2; ni++)
            bfr[ni] = *(const short8*)&Ws[(quad * 64 + wave_oc + ni * 16 + lane16) * 8];
#pragma unroll
        for (int mi = 0; mi < 4; mi++)
#pragma unroll
            for (int ni = 0; ni < 2; ni++)
                acc[mi][ni] = __builtin_amdgcn_mfma_f32_16x16x32_bf16(af[mi], bfr[ni],
                                                                     acc[mi][ni], 0, 0, 0);
    }
    // epilogue -> pixel-major rpn
#pragma unroll
    for (int ni = 0; ni < 2; ni++) {
        int oc = oct * 64 + wave_oc + ni * 16 + lane16;
        float bias = Bs[oc];
#pragma unroll
        for (int mi = 0; mi < 4; mi++) {
#pragma unroll
            for (int r = 0; r < 4; r++) {
                int px = wave_px + mi * 16 + quad * 4 + r;
                if (px < 120)
                    out[(size_t)(h * 120 + px) * 512 + oc] =
                        f2bf(fmaxf(acc[mi][ni][r] + bias, 0.f));
            }
        }
    }
}

// ---------------- heads via MFMA: [9120 px][512] @ [54][512]^T -> cls_s, bbox_p ----------------
// grid 72, block 256. Block tile 128 px x 64 oc (54 used), K=512 in 16 chunks.
__global__ __launch_bounds__(256) void heads_mfma_kernel(
    const unsigned short* __restrict__ rpn,   // [9120][512] bf16
    const float* __restrict__ cw, const float* __restrict__ cb,
    const float* __restrict__ bw, const float* __restrict__ bb,
    float* __restrict__ cls_s, float* __restrict__ bbox_p) {
    __shared__ __align__(16) unsigned short As[128 * 42];
    __shared__ __align__(16) unsigned short Ws[64 * 42];
    const int tid = threadIdx.x;
    const int px0 = blockIdx.x * 128;
    const int lane = tid & 63, wv = tid >> 6;
    const int lane16 = lane & 15, quad = lane >> 4;
    const int wave_px = (wv & 1) * 64, wave_oc = (wv >> 1) * 32;

    f32x4 acc[4][2];
#pragma unroll
    for (int mi = 0; mi < 4; mi++)
#pragma unroll
        for (int ni = 0; ni < 2; ni++) acc[mi][ni] = (f32x4){0.f, 0.f, 0.f, 0.f};

    const int wn = tid >> 2, wseg = tid & 3;   // W staging: n, 8-float segment
    const float* wsrc = (wn < 18) ? (cw + (size_t)wn * 512)
                      : (wn < 54) ? (bw + (size_t)(wn - 18) * 512) : nullptr;

    short8 rA[2];
    float4 rw0, rw1;
    {
        int k0 = 0;
#pragma unroll
        for (int u = 0; u < 2; u++) {
            int lid = tid + 256 * u;
            int row = lid >> 2, seg = lid & 3;
            int px = px0 + row;
            rA[u] = (px < NPIX) ? *(const short8*)(rpn + (size_t)px * 512 + k0 + seg * 8)
                                : (short8){0, 0, 0, 0, 0, 0, 0, 0};
        }
        if (wsrc) {
            rw0 = *(const float4*)(wsrc + k0 + wseg * 8);
            rw1 = *(const float4*)(wsrc + k0 + wseg * 8 + 4);
        } else { rw0 = make_float4(0, 0, 0, 0); rw1 = rw0; }
    }
    for (int c = 0; c < 16; ++c) {
        __syncthreads();
#pragma unroll
        for (int u = 0; u < 2; u++) {
            int lid = tid + 256 * u;
            int row = lid >> 2, seg = lid & 3;
            *(short8*)&As[row * 42 + seg * 8] = rA[u];
        }
        {
            short8 wb;
            float* p0 = (float*)&rw0;
            float* p1 = (float*)&rw1;
#pragma unroll
            for (int v = 0; v < 4; v++) { wb[v] = (short)f2bf(p0[v]); wb[4 + v] = (short)f2bf(p1[v]); }
            *(short8*)&Ws[wn * 42 + wseg * 8] = wb;
        }
        if (c + 1 < 16) {
            int k0 = (c + 1) * 32;
#pragma unroll
            for (int u = 0; u < 2; u++) {
                int lid = tid + 256 * u;
                int row = lid >> 2, seg = lid & 3;
                int px = px0 + row;
                rA[u] = (px < NPIX) ? *(const short8*)(rpn + (size_t)px * 512 + k0 + seg * 8)
                                    : (short8){0, 0, 0, 0, 0, 0, 0, 0};
            }
            if (wsrc) {
                rw0 = *(const float4*)(wsrc + k0 + wseg * 8);
                rw1 = *(const float4*)(wsrc + k0 + wseg * 8 + 4);
            }
        }
        __syncthreads();
        short8 af[4], bfr[2];
#pragma unroll
        for (int mi = 0; mi < 4; mi++)
            af[mi] = *(const short8*)&As[(wave_px + mi * 16 + lane16) * 42 + quad * 8];
#pragma unroll
        for (int ni = 0; ni < 2; ni++)
            bfr[ni] = *(const short8*)&Ws[(wave_oc + ni * 16 + lane16) * 42 + quad * 8];
#pragma unroll
        for (int mi = 0; mi < 4; mi++)
#pragma unroll
            for (int ni = 0; ni < 2; ni++)
                acc[mi][ni] = __builtin_amdgcn_mfma_f32_16x16x32_bf16(af[mi], bfr[ni],
                                                                     acc[mi][ni], 0, 0, 0);
    }
#pragma unroll
    for (int ni = 0; ni < 2; ni++) {
        int oc = wave_oc + ni * 16 + lane16;
        float* dst;
        float bias;
        if (oc < 18) { dst = cls_s + (size_t)oc * NPIX; bias = cb[oc]; }
        else if (oc < 54) { dst = bbox_p + (size_t)(oc - 18) * NPIX; bias = bb[oc - 18]; }
        else continue;
#pragma unroll
        for (int mi = 0; mi < 4; mi++) {
            int pxb = px0 + wave_px + mi * 16 + quad * 4;
            if (pxb < NPIX) {
                float4 v = make_float4(acc[mi][ni][0] + bias, acc[mi][ni][1] + bias,
                                       acc[mi][ni][2] + bias, acc[mi][ni][3] + bias);
                *(float4*)(dst + pxb) = v;
            }
        }
    }
}

// ---------------- decode ----------------
__global__ void decode_kernel(const float* __restrict__ cls_s, const float* __restrict__ bbox_p,
                              const float* __restrict__ anchors,
                              unsigned int* __restrict__ keys, float* __restrict__ boxes) {
    int i = blockIdx.x * 256 + threadIdx.x;
    if (i >= NANCH) return;
    int pix = i / AA;
    int a = i - pix * AA;
    float s0 = cls_s[(size_t)a * NPIX + pix];
    float s1 = cls_s[(size_t)(AA + a) * NPIX + pix];
    float d = s1 - s0;
    unsigned int u = __float_as_uint(d);
    keys[i] = (u & 0x80000000u) ? ~u : (u | 0x80000000u);

    float dx = bbox_p[(size_t)(4 * a + 0) * NPIX + pix];
    float dy = bbox_p[(size_t)(4 * a + 1) * NPIX + pix];
    float dw = bbox_p[(size_t)(4 * a + 2) * NPIX + pix];
    float dh = bbox_p[(size_t)(4 * a + 3) * NPIX + pix];
    float ax1 = anchors[(size_t)i * 4 + 0];
    float ay1 = anchors[(size_t)i * 4 + 1];
    float ax2 = anchors[(size_t)i * 4 + 2];
    float ay2 = anchors[(size_t)i * 4 + 3];
    float aw = ax2 - ax1 + 1.f;
    float ah = ay2 - ay1 + 1.f;
    float acx = ax1 + 0.5f * aw;
    float acy = ay1 + 0.5f * ah;
    float pcx = dx * aw + acx;
    float pcy = dy * ah + acy;
    float pw = __expf(dw) * aw;
    float ph = __expf(dh) * ah;
    const float XMAX = 16.f * WW - 1.f;
    const float YMAX = 16.f * HH - 1.f;
    boxes[(size_t)i * 4 + 0] = fminf(fmaxf(pcx - 0.5f * pw, 0.f), XMAX);
    boxes[(size_t)i * 4 + 1] = fminf(fmaxf(pcy - 0.5f * ph, 0.f), YMAX);
    boxes[(size_t)i * 4 + 2] = fminf(fmaxf(pcx + 0.5f * pw, 0.f), XMAX);
    boxes[(size_t)i * 4 + 3] = fminf(fmaxf(pcy + 0.5f * ph, 0.f), YMAX);
}

// ---------------- exact top-k ----------------
__global__ __launch_bounds__(1024) void topk_kernel(const unsigned int* __restrict__ keys,
                                                    int* __restrict__ top_idx) {
    const int N = NANCH, K = TOPN;
    __shared__ unsigned int s_prefix;
    __shared__ int s_k;
    __shared__ unsigned int hist[256];
    __shared__ int s_ngt, s_neq;
    __shared__ unsigned long long s_sel[512];
    __shared__ int s_eq[1024];
    int tid = threadIdx.x;
    if (tid == 0) { s_prefix = 0u; s_k = K; }
    __syncthreads();

    for (int d = 3; d >= 0; --d) {
        if (tid < 256) hist[tid] = 0u;
        __syncthreads();
        unsigned int pfx = s_prefix;
        unsigned int maskHigh = (d == 3) ? 0u : ~((1u << ((d + 1) * 8)) - 1u);
        int shift = d * 8;
        for (int i = tid; i < N; i += 1024) {
            unsigned int k = keys[i];
            if ((k & maskHigh) == (pfx & maskHigh))
                atomicAdd(&hist[(k >> shift) & 255u], 1u);
        }
        __syncthreads();
        if (tid == 0) {
            int kk = s_k;
            int cum = 0;
            unsigned int sel = 0;
            for (int v = 255; v >= 0; v--) {
                int hcnt = (int)hist[v];
                if (cum + hcnt >= kk) { sel = (unsigned int)v; s_k = kk - cum; break; }
                cum += hcnt;
            }
            s_prefix = pfx | (sel << shift);
        }
        __syncthreads();
    }
    unsigned int T = s_prefix;
    int krem = s_k;
    if (tid == 0) { s_ngt = 0; s_neq = 0; }
    __syncthreads();
    for (int i = tid; i < N; i += 1024) {
        unsigned int k = keys[i];
        if (k > T) {
            int p = atomicAdd(&s_ngt, 1);
            if (p < 512)
                s_sel[p] = ((unsigned long long)k << 32) | (unsigned int)(~(unsigned int)i);
        } else if (k == T) {
            int p = atomicAdd(&s_neq, 1);
            if (p < 1024) s_eq[p] = i;
        }
    }
    __syncthreads();
    int ngt = min(s_ngt, 512);
    int neq = min(s_neq, 1024);
    for (int e = tid; e < neq; e += 1024) {
        int idx = s_eq[e];
        int rank = 0;
        for (int j = 0; j < neq; j++)
            if (s_eq[j] < idx) rank++;
        if (rank < krem && ngt + rank < 512)
            s_sel[ngt + rank] = ((unsigned long long)T << 32) | (unsigned int)(~(unsigned int)idx);
    }
    __syncthreads();
    for (int p = K + tid; p < 512; p += 1024) s_sel[p] = 0ULL;
    __syncthreads();
    for (unsigned int k2 = 2; k2 <= 512; k2 <<= 1) {
        for (unsigned int j = k2 >> 1; j > 0; j >>= 1) {
            if (tid < 512) {
                int i = tid;
                int ixj = i ^ (int)j;
                if (ixj > i) {
                    unsigned long long a = s_sel[i], cc = s_sel[ixj];
                    bool up = ((i & k2) == 0);
                    if (up ? (a > cc) : (a < cc)) { s_sel[i] = cc; s_sel[ixj] = a; }
                }
            }
            __syncthreads();
        }
    }
    if (tid < K)
        top_idx[tid] = (int)(~(unsigned int)(s_sel[511 - tid] & 0xFFFFFFFFull));
}

// ---------------- roi align from Fpix -> pooled (n,q,c) bf16 ----------------
__global__ __launch_bounds__(256) void roialign_kernel(
    const unsigned short* __restrict__ Fpix, const float* __restrict__ boxes,
    const int* __restrict__ top_idx, unsigned short* __restrict__ pooled) {
    int n = blockIdx.x;
    int q = blockIdx.y;
    int ph = q / 7, pw = q - ph * 7;
    int bi = top_idx[n];
    float x1 = boxes[(size_t)bi * 4 + 0] * (1.f / 16.f);
    float y1 = boxes[(size_t)bi * 4 + 1] * (1.f / 16.f);
    float x2 = boxes[(size_t)bi * 4 + 2] * (1.f / 16.f);
    float y2 = boxes[(size_t)bi * 4 + 3] * (1.f / 16.f);
    float gx = (pw + 0.5f) / 7.f;
    float gy = (ph + 0.5f) / 7.f;
    float xs = fminf(fmaxf(x1 + (x2 - x1) * gx, 0.f), (float)(WW - 1));
    float ys = fminf(fmaxf(y1 + (y2 - y1) * gy, 0.f), (float)(HH - 1));
    float x0f = floorf(xs), y0f = floorf(ys);
    int x0 = (int)x0f, y0 = (int)y0f;
    int x1i = min(x0 + 1, WW - 1);
    int y1i = min(y0 + 1, HH - 1);
    float wx = xs - x0f, wy = ys - y0f;
    float w00 = (1.f - wy) * (1.f - wx), w01 = (1.f - wy) * wx;
    float w10 = wy * (1.f - wx), w11 = wy * wx;
    const unsigned short* r00 = Fpix + (size_t)((y0 + 1) * PW + x0 + 1) * 1024;
    const unsigned short* r01 = Fpix + (size_t)((y0 + 1) * PW + x1i + 1) * 1024;
    const unsigned short* r10 = Fpix + (size_t)((y1i + 1) * PW + x0 + 1) * 1024;
    const unsigned short* r11 = Fpix + (size_t)((y1i + 1) * PW + x1i + 1) * 1024;
    unsigned short* dst = pooled + (size_t)n * KFC + (size_t)q * CIN;
    int c = threadIdx.x * 4;
    ushort4 a = *(const ushort4*)(r00 + c);
    ushort4 b = *(const ushort4*)(r01 + c);
    ushort4 cc = *(const ushort4*)(r10 + c);
    ushort4 d = *(const ushort4*)(r11 + c);
    ushort4 o;
    o.x = f2bf(w00 * bf2f(a.x) + w01 * bf2f(b.x) + w10 * bf2f(cc.x) + w11 * bf2f(d.x));
    o.y = f2bf(w00 * bf2f(a.y) + w01 * bf2f(b.y) + w10 * bf2f(cc.y) + w11 * bf2f(d.y));
    o.z = f2bf(w00 * bf2f(a.z) + w01 * bf2f(b.z) + w10 * bf2f(cc.z) + w11 * bf2f(d.z));
    o.w = f2bf(w00 * bf2f(a.w) + w01 * bf2f(b.w) + w10 * bf2f(cc.w) + w11 * bf2f(d.w));
    *(ushort4*)(dst + c) = o;
}

// ---------------- FC GEMM via MFMA: fc7 += pooled(300x50176 bf16) @ fc_w(fp32->bf16) ----------
// grid 256: kz = b&7 (XCD-affine), j-tile = b>>3 (64 cols). Block: 320 px x 64 col.
__global__ __launch_bounds__(256) void fc_mfma_kernel(
    const unsigned short* __restrict__ pooled, const float* __restrict__ fc_w,
    float* __restrict__ fc7) {
    __shared__ __align__(16) unsigned short As[320 * 42];
    __shared__ __align__(16) unsigned short Ws[64 * 42];
    const int tid = threadIdx.x;
    const int b = blockIdx.x;
    const int kz = b & 7;
    const int j0 = (b >> 3) * 64;
    const int lane = tid & 63, wv = tid >> 6;
    const int lane16 = lane & 15, quad = lane >> 4;
    const int m0 = wv * 80;
    const int kbase = kz * 6272;
    const int g = tid >> 4;              // W staging: krow pair 2g, 2g+1
    const int col4 = (tid & 15) * 4;

    f32x4 acc[5][4];
#pragma unroll
    for (int mi = 0; mi < 5; mi++)
#pragma unroll
        for (int ni = 0; ni < 4; ni++) acc[mi][ni] = (f32x4){0.f, 0.f, 0.f, 0.f};

    short8 rA[5];
    float4 rW0[2], rW1[2];

#define LOAD_A(cIdx)                                                              \
    {                                                                             \
        int k0_ = kbase + (cIdx) * 32;                                            \
        _Pragma("unroll")                                                         \
        for (int i = 0; i < 5; i++) {                                             \
            int lid = tid + 256 * i;                                              \
            int row = lid >> 2, seg = lid & 3;                                    \
            rA[i] = (row < TOPN)                                                  \
                  ? *(const short8*)(pooled + (size_t)row * KFC + k0_ + seg * 8)  \
                  : (short8){0, 0, 0, 0, 0, 0, 0, 0};                             \
        }                                                                         \
    }
#define LOAD_W(cIdx, dst)                                                         \
    {                                                                             \
        int k0_ = kbase + (cIdx) * 32;                                            \
        int q_ = k0_ >> 10, c0_ = k0_ & 1023;                                     \
        _Pragma("unroll")                                                         \
        for (int u = 0; u < 2; u++)                                               \
            dst[u] = *(const float4*)(fc_w +                                      \
                ((size_t)(c0_ + 2 * g + u) * 49 + q_) * FCDIM + j0 + col4);       \
    }

    LOAD_A(0);
    LOAD_W(0, rW0);
    LOAD_W(1, rW1);

    for (int c = 0; c < 196; ++c) {
        __syncthreads();
#pragma unroll
        for (int i = 0; i < 5; i++) {
            int lid = tid + 256 * i;
            int row = lid >> 2, seg = lid & 3;
            *(short8*)&As[row * 42 + seg * 8] = rA[i];
        }
        {
            float* p0 = (float*)&rW0[0];
            float* p1 = (float*)&rW0[1];
#pragma unroll
            for (int v = 0; v < 4; v++) {
                unsigned int pk = (unsigned int)f2bf(p0[v]) | ((unsigned int)f2bf(p1[v]) << 16);
                *(unsigned int*)&Ws[(col4 + v) * 42 + 2 * g] = pk;
            }
        }
        if (c + 1 < 196) LOAD_A(c + 1);
        rW0[0] = rW1[0]; rW0[1] = rW1[1];
        if (c + 2 < 196) LOAD_W(c + 2, rW1);
        __syncthreads();
        short8 af[5], bfr[4];
#pragma unroll
        for (int mi = 0; mi < 5; mi++)
            af[mi] = *(const short8*)&As[(m0 + mi * 16 + lane16) * 42 + quad * 8];
#pragma unroll
        for (int ni = 0; ni < 4; ni++)
            bfr[ni] = *(const short8*)&Ws[(ni * 16 + lane16) * 42 + quad * 8];
#pragma unroll
        for (int mi = 0; mi < 5; mi++)
#pragma unroll
            for (int ni = 0; ni < 4; ni++)
                acc[mi][ni] = __builtin_amdgcn_mfma_f32_16x16x32_bf16(af[mi], bfr[ni],
                                                                     acc[mi][ni], 0, 0, 0);
    }
#undef LOAD_A
#undef LOAD_W
#pragma unroll
    for (int mi = 0; mi < 5; mi++) {
#pragma unroll
        for (int r = 0; r < 4; r++) {
            int m = m0 + mi * 16 + quad * 4 + r;
            if (m < TOPN) {
#pragma unroll
                for (int ni = 0; ni < 4; ni++)
                    atomicAdd(&fc7[(size_t)m * FCDIM + j0 + ni * 16 + lane16], acc[mi][ni][r]);
            }
        }
    }
}

// ---------------- fc7 bias + relu ----------------
__global__ void bias_relu_kernel(float* __restrict__ fc7, const float* __restrict__ fc_b) {
    int i = blockIdx.x * 256 + threadIdx.x;
    if (i < TOPN * FCDIM)
        fc7[i] = fmaxf(fc7[i] + fc_b[i & (FCDIM - 1)], 0.f);
}

// ---------------- head GEMMs ----------------
__global__ __launch_bounds__(128) void head_gemm_kernel(
    const float* __restrict__ fc7,
    const float* __restrict__ cw, const float* __restrict__ cb,
    const float* __restrict__ bw, const float* __restrict__ bb,
    float* __restrict__ cls_score, float* __restrict__ bbox_pred) {
    int n = blockIdx.x;
    __shared__ float row[FCDIM];
    for (int k = threadIdx.x; k < FCDIM; k += 128) row[k] = fc7[(size_t)n * FCDIM + k];
    __syncthreads();
    int t = threadIdx.x;
    if (t < 21) {
        float acc = 0.f;
        for (int k = 0; k < FCDIM; k += 4) {
#pragma unroll
            for (int u = 0; u < 4; u++) acc += row[k + u] * cw[(size_t)(k + u) * 21 + t];
        }
        cls_score[n * 21 + t] = acc + cb[t];
    } else if (t < 105) {
        int oc = t - 21;
        float acc = 0.f;
        for (int k = 0; k < FCDIM; k += 4) {
#pragma unroll
            for (int u = 0; u < 4; u++) acc += row[k + u] * bw[(size_t)(k + u) * 84 + oc];
        }
        bbox_pred[n * 84 + oc] = acc + bb[oc];
    }
}

// ---------------- losses ----------------
__device__ __forceinline__ void block_atomic_acc(float v, float* dst) {
    for (int o = 32; o > 0; o >>= 1) v += __shfl_down(v, o);
    if ((threadIdx.x & 63) == 0) atomicAdd(dst, v);
}

__global__ void loss_rpn_ce_kernel(const float* __restrict__ cls_s,
                                   const int* __restrict__ labels, float* __restrict__ acc) {
    int i = blockIdx.x * 256 + threadIdx.x;
    float ce = 0.f, cnt = 0.f;
    if (i < NANCH) {
        int lab = labels[i];
        if (lab != -1) {
            int a = i / NPIX, pix = i - a * NPIX;
            float s0 = cls_s[(size_t)a * NPIX + pix];
            float s1 = cls_s[(size_t)(AA + a) * NPIX + pix];
            float m = fmaxf(s0, s1);
            float lse = m + logf(expf(s0 - m) + expf(s1 - m));
            ce = lse - (lab ? s1 : s0);
            cnt = 1.f;
        }
    }
    block_atomic_acc(ce, &acc[0]);
    block_atomic_acc(cnt, &acc[1]);
}

__global__ void loss_rpn_bbox_kernel(const float* __restrict__ bbox_p,
                                     const float* __restrict__ tgt,
                                     const float* __restrict__ biw,
                                     const float* __restrict__ bow, float* __restrict__ acc) {
    int e = blockIdx.x * 256 + threadIdx.x;
    float contrib = 0.f;
    if (e < NPIX * 36) {
        int pix = e / 36, c = e - pix * 36;
        float pred = bbox_p[(size_t)c * NPIX + pix];
        float d = biw[e] * (pred - tgt[e]);
        float ad = fabsf(d);
        float l = (ad < (1.f / 9.f)) ? d * d * 4.5f : ad - (1.f / 18.f);
        contrib = bow[e] * l;
    }
    block_atomic_acc(contrib, &acc[2]);
}

__global__ void loss_cls_kernel(const float* __restrict__ cls_score,
                                const int* __restrict__ labels, float* __restrict__ acc) {
    int n = blockIdx.x * 256 + threadIdx.x;
    float ce = 0.f;
    if (n < TOPN) {
        const float* lg = cls_score + n * 21;
        float m = lg[0];
        for (int j = 1; j < 21; j++) m = fmaxf(m, lg[j]);
        float s = 0.f;
        for (int j = 0; j < 21; j++) s += expf(lg[j] - m);
        ce = m + logf(s) - lg[labels[n]];
    }
    block_atomic_acc(ce, &acc[3]);
}

__global__ void loss_roi_bbox_kernel(const float* __restrict__ bbox_pred,
                                     const float* __restrict__ tgt,
                                     const float* __restrict__ biw,
                                     const float* __restrict__ bow, float* __restrict__ acc) {
    int e = blockIdx.x * 256 + threadIdx.x;
    float contrib = 0.f;
    if (e < TOPN * 84) {
        float d = biw[e] * (bbox_pred[e] - tgt[e]);
        float ad = fabsf(d);
        float l = (ad < 1.f) ? 0.5f * d * d : ad - 0.5f;
        contrib = bow[e] * l;
    }
    block_atomic_acc(contrib, &acc[4]);
}

__global__ void finalize_kernel(const float* __restrict__ acc, float* __restrict__ out) {
    out[0] = acc[0] / fmaxf(acc[1], 1.f) + acc[2]
           + acc[3] * (1.f / TOPN) + acc[4] * (1.f / TOPN);
}

// ---------------- launch ----------------
extern "C" void kernel_launch(void* const* d_in, const int* in_sizes, int n_in,
                              void* d_out, int out_size, void* d_ws, size_t ws_size,
                              hipStream_t stream) {
    const float* net_conv   = (const float*)d_in[0];
    const float* rpn_w      = (const float*)d_in[1];
    const float* rpn_b      = (const float*)d_in[2];
    const float* rpn_cls_w  = (const float*)d_in[3];
    const float* rpn_cls_b  = (const float*)d_in[4];
    const float* rpn_bbox_w = (const float*)d_in[5];
    const float* rpn_bbox_b = (const float*)d_in[6];
    const float* fc_w       = (const float*)d_in[7];
    const float* fc_b       = (const float*)d_in[8];
    const float* cls_w      = (const float*)d_in[9];
    const float* cls_b      = (const float*)d_in[10];
    const float* bbox_w     = (const float*)d_in[11];
    const float* bbox_b     = (const float*)d_in[12];
    const float* anchors    = (const float*)d_in[13];
    const float* rpn_bt     = (const float*)d_in[14];
    const float* rpn_biw    = (const float*)d_in[15];
    const float* rpn_bow    = (const float*)d_in[16];
    const float* roi_bt     = (const float*)d_in[17];
    const float* roi_biw    = (const float*)d_in[18];
    const float* roi_bow    = (const float*)d_in[19];
    const int* rpn_labels   = (const int*)d_in[20];
    const int* roi_labels   = (const int*)d_in[21];

    char* base = (char*)d_ws;
    unsigned short* Fpix = (unsigned short*)base;
    const size_t FPIX_BYTES = (size_t)FPIX_ROWS * 1024 * 2;  // 20,463,616
    unsigned short* Wb = (unsigned short*)(base + FPIX_BYTES);
    unsigned short* rpn = (unsigned short*)(base + 29900800);  // [9120][512] bf16
    unsigned short* pooled = (unsigned short*)(base + FPIX_BYTES);
    size_t off = 50569216;
    float* cls_s = (float*)(base + off);      off += 656640;
    float* bbox_p = (float*)(base + off);     off += 1313280;
    unsigned int* keys = (unsigned int*)(base + off); off += 328448;
    float* boxes = (float*)(base + off);      off += 1313280;
    int* top_idx = (int*)(base + off);        off += 1280;
    float* cls_score = (float*)(base + off);  off += 25600;
    float* bbox_pred = (float*)(base + off);  off += 100864;
    float* fc7 = (float*)(base + off);        off += 2457600;
    float* accum = (float*)(base + off);      off += 256;
    float* out = (float*)d_out;

    zero4_kernel<<<(int)((FPIX_BYTES / 16 + 255) / 256), 256, 0, stream>>>((float4*)Fpix,
                                                                           (int)(FPIX_BYTES / 16));
    fpix_fill_kernel<<<dim3(143, 16), 256, 0, stream>>>(net_conv, Fpix);
    wb_fill_kernel<<<2048, 256, 0, stream>>>(rpn_w, Wb);
    zero_kernel<<<2401, 256, 0, stream>>>(fc7, TOPN * FCDIM + 16);

    conv_mfma_kernel<<<dim3(8, 76), 256, 0, stream>>>(Fpix, Wb, rpn_b, rpn);
    heads_mfma_kernel<<<72, 256, 0, stream>>>(rpn, rpn_cls_w, rpn_cls_b,
                                              rpn_bbox_w, rpn_bbox_b, cls_s, bbox_p);
    decode_kernel<<<(NANCH + 255) / 256, 256, 0, stream>>>(cls_s, bbox_p, anchors, keys, boxes);
    topk_kernel<<<1, 1024, 0, stream>>>(keys, top_idx);
    roialign_kernel<<<dim3(300, 49), 256, 0, stream>>>(Fpix, boxes, top_idx, pooled);
    fc_mfma_kernel<<<256, 256, 0, stream>>>(pooled, fc_w, fc7);
    bias_relu_kernel<<<(TOPN * FCDIM + 255) / 256, 256, 0, stream>>>(fc7, fc_b);
    head_gemm_kernel<<<300, 128, 0, stream>>>(fc7, cls_w, cls_b, bbox_w, bbox_b,
                                              cls_score, bbox_pred);
    loss_rpn_ce_kernel<<<(NANCH + 255) / 256, 256, 0, stream>>>(cls_s, rpn_labels, accum);
    loss_rpn_bbox_kernel<<<(NPIX * 36 + 255) / 256, 256, 0, stream>>>(bbox_p, rpn_bt,
                                                                      rpn_biw, rpn_bow, accum);
    loss_cls_kernel<<<2, 256, 0, stream>>>(cls_score, roi_labels, accum);
    loss_roi_bbox_kernel<<<(TOPN * 84 + 255) / 256, 256, 0, stream>>>(bbox_pred, roi_bt,
                                                                      roi_biw, roi_bow, accum);
    finalize_kernel<<<1, 1, 0, stream>>>(accum, out);
}